// Round 8
// baseline (967.784 us; speedup 1.0000x reference)
//
#include <hip/hip_runtime.h>
#include <hip/hip_bf16.h>

#define DIN 128
#define HID 32
#define EPS 1e-5f
#define FXS 16777216.0f             // 2^24 fixed-point scale for deg accumulation
#define FXI 5.9604644775390625e-8f  // 2^-24
#define NSPLIT 4                    // src-quartile sub-bins, materialized as 4 gather launches

typedef unsigned int u32;
typedef unsigned short u16;
typedef unsigned long long u64;

// extract bf16 half (hi=0 -> low 16 bits = even channel) as float
__device__ __forceinline__ float bfx(u32 v, int hi) {
    return __uint_as_float(hi ? (v & 0xffff0000u) : (v << 16));
}

__device__ __forceinline__ u16 f2bf(float f) {
    __hip_bfloat16 h = __float2bfloat16(f);
    return *reinterpret_cast<u16*>(&h);
}

// ---------------- init: zero u64 count/deg accumulator + BN stats ----------------
__global__ void init_cnt(u64* __restrict__ cnt64, float* __restrict__ stats, int n4) {
    int i = blockIdx.x * blockDim.x + threadIdx.x;
    if (i < n4) cnt64[i] = 0ull;
    if (i < 192) stats[i] = 0.f;
}

// one u64 atomic per edge into bin (q*N + col): count(hi32) + fixpoint w(lo32)
__global__ void hist_rank(const int* __restrict__ row, const int* __restrict__ col,
                          const float* __restrict__ w, u64* __restrict__ cnt64,
                          int* __restrict__ rank, int E, int n, u32 qdiv) {
    int e = blockIdx.x * blockDim.x + threadIdx.x;
    if (e < E) {
        int c = col[e];
        u32 q = (u32)row[e] / qdiv;
        u32 fx = (u32)(w[e] * FXS + 0.5f);
        u64 old = atomicAdd(&cnt64[(size_t)q * n + c], (1ull << 32) | (u64)fx);
        rank[e] = (int)(old >> 32);
    }
}

// per-node: 4 sub-bin counts -> rowptr (pre-scan), total deg -> dinv
__global__ void finalize_deg(const u64* __restrict__ cnt64, int* __restrict__ rowptr,
                             float* __restrict__ dinv, int n) {
    int i = blockIdx.x * blockDim.x + threadIdx.x;
    if (i < n) {
        float degw = 0.f;
#pragma unroll
        for (int q = 0; q < NSPLIT; ++q) {
            u64 v = cnt64[(size_t)q * n + i];
            rowptr[q * n + i] = (int)(v >> 32);
            degw += (float)(u32)v;
        }
        dinv[i] = rsqrtf(1.0f + degw * FXI);  // +1 self loop
    }
}

// ---------------- exclusive scan (multi-level) ----------------
__global__ void scan_blocks(int* __restrict__ data, int* __restrict__ bsum, int n) {
    __shared__ int s[256];
    int i = blockIdx.x * 256 + threadIdx.x;
    int v = (i < n) ? data[i] : 0;
    s[threadIdx.x] = v;
    __syncthreads();
    for (int off = 1; off < 256; off <<= 1) {
        int t = (threadIdx.x >= off) ? s[threadIdx.x - off] : 0;
        __syncthreads();
        s[threadIdx.x] += t;
        __syncthreads();
    }
    if (i < n) data[i] = s[threadIdx.x] - v;  // exclusive
    if (threadIdx.x == 255) bsum[blockIdx.x] = s[255];
}

__global__ void scan_tops(int* __restrict__ bsum, int nb) {
    __shared__ int s[512];
    int v = (threadIdx.x < nb) ? bsum[threadIdx.x] : 0;
    s[threadIdx.x] = v;
    __syncthreads();
    for (int off = 1; off < 512; off <<= 1) {
        int t = (threadIdx.x >= off) ? s[threadIdx.x - off] : 0;
        __syncthreads();
        s[threadIdx.x] += t;
        __syncthreads();
    }
    if (threadIdx.x < nb) bsum[threadIdx.x] = s[threadIdx.x] - v;  // exclusive
}

__global__ void scan_addback(int* __restrict__ data, const int* __restrict__ bsum,
                             int n, int E) {
    int i = blockIdx.x * 256 + threadIdx.x;
    if (i < n) data[i] += bsum[blockIdx.x];
    if (i == n) data[n] = E;  // sentinel end
}

// ---------------- atomic-free scatter into split CSR ----------------
__global__ void scatter_pos(const int* __restrict__ row, const int* __restrict__ col,
                            const float* __restrict__ w, const float* __restrict__ dinv,
                            const int* __restrict__ rowptr, const int* __restrict__ rank,
                            int2* __restrict__ esort, int E, int n, u32 qdiv) {
    int e = blockIdx.x * blockDim.x + threadIdx.x;
    if (e < E) {
        int r = row[e], c = col[e];
        u32 q = (u32)r / qdiv;
        float nv = dinv[r] * w[e] * dinv[c];
        int pos = rowptr[(size_t)q * n + c] + rank[e];
        esort[pos] = make_int2(r, __float_as_int(nv));
    }
}

// ---------------- layer-0 GEMM (x fp32 -> h bf16) ----------------
__global__ void gemm_din(const float* __restrict__ x, const float* __restrict__ W,
                         u16* __restrict__ hb, int n) {
    __shared__ float Wl[DIN * HID];
    for (int i = threadIdx.x; i < DIN * HID; i += blockDim.x) Wl[i] = W[i];
    __syncthreads();
    int ch = threadIdx.x & 31;
    int node = blockIdx.x * 8 + (threadIdx.x >> 5);
    if (node >= n) return;
    const float* xr = x + (size_t)node * DIN;
    float acc = 0.f;
#pragma unroll 8
    for (int k = 0; k < DIN; ++k) acc += xr[k] * Wl[k * HID + ch];
    hb[node * HID + ch] = f2bf(acc);
}

// ---------------- hidden GEMM with fused BN+ReLU on the input ----------------
__global__ void gemm_hid_bn(const float* __restrict__ a, const float* __restrict__ W,
                            const float* __restrict__ stats, const float* __restrict__ g,
                            const float* __restrict__ be, u16* __restrict__ hb,
                            int n, float invN) {
    __shared__ float Wl[HID * HID];
    __shared__ float sc[HID], sh[HID];
    int t = threadIdx.x;
    for (int i = t; i < HID * HID; i += blockDim.x) Wl[i] = W[i];
    if (t < HID) {
        float mu = stats[t] * invN;
        float var = stats[32 + t] * invN - mu * mu;
        float s = rsqrtf(var + EPS) * g[t];
        sc[t] = s;
        sh[t] = be[t] - mu * s;
    }
    __syncthreads();
    int ch = t & 31;
    int node = blockIdx.x * 8 + (t >> 5);
    if (node >= n) return;
    const float* ar = a + (size_t)node * HID;
    float acc = 0.f;
#pragma unroll
    for (int k = 0; k < HID; ++k) {
        float v = fmaxf(ar[k] * sc[k] + sh[k], 0.f);
        acc += v * Wl[k * HID + ch];
    }
    hb[node * HID + ch] = f2bf(acc);
}

// ---------------- one quartile pass of the split-CSR gather ----------------
// flags bit0: first pass (init acc with self-loop + bias, no read of aggin)
// flags bit1: last pass of output layer (apply ReLU)
// rp = rowptr + q*N; pass q touches only h rows in src-quartile q (L2-resident slice)
__global__ void gather_pass(const u32* __restrict__ h2, const int* __restrict__ rp,
                            const int2* __restrict__ esort, const float* __restrict__ dinv,
                            const float* __restrict__ b, const float* __restrict__ aggin,
                            float* __restrict__ aggout, int n, int flags) {
    int ch = threadIdx.x & 31;
    int node = blockIdx.x * 8 + (threadIdx.x >> 5);
    if (node >= n) return;
    int p = ch >> 1, hi = ch & 1;
    float acc;
    if (flags & 1) {
        float dv = dinv[node];
        acc = dv * dv * bfx(h2[node * 16 + p], hi) + b[ch];
    } else {
        acc = aggin[node * HID + ch];
    }
    int start = rp[node], end = rp[node + 1];
    int j = start;
    for (; j + 4 <= end; j += 4) {
        int2 e0 = esort[j];
        int2 e1 = esort[j + 1];
        int2 e2 = esort[j + 2];
        int2 e3 = esort[j + 3];
        u32 v0 = h2[e0.x * 16 + p];
        u32 v1 = h2[e1.x * 16 + p];
        u32 v2 = h2[e2.x * 16 + p];
        u32 v3 = h2[e3.x * 16 + p];
        acc += __int_as_float(e0.y) * bfx(v0, hi);
        acc += __int_as_float(e1.y) * bfx(v1, hi);
        acc += __int_as_float(e2.y) * bfx(v2, hi);
        acc += __int_as_float(e3.y) * bfx(v3, hi);
    }
    for (; j < end; ++j) {
        int2 ed = esort[j];
        acc += __int_as_float(ed.y) * bfx(h2[ed.x * 16 + p], hi);
    }
    if (flags & 2) acc = fmaxf(acc, 0.f);
    aggout[node * HID + ch] = acc;
}

// ---------------- BN stats reduce ----------------
__global__ void bn_reduce(const float* __restrict__ agg, float* __restrict__ stats, int n) {
    __shared__ float s1[256], s2[256];
    int ch = threadIdx.x & 31, rg = threadIdx.x >> 5;
    float a = 0.f, b = 0.f;
    for (int node = blockIdx.x * 8 + rg; node < n; node += gridDim.x * 8) {
        float v = agg[node * HID + ch];
        a += v;
        b += v * v;
    }
    s1[threadIdx.x] = a;
    s2[threadIdx.x] = b;
    __syncthreads();
    if (threadIdx.x < 32) {
        float ta = 0.f, tb = 0.f;
#pragma unroll
        for (int j = 0; j < 8; ++j) {
            ta += s1[j * 32 + threadIdx.x];
            tb += s2[j * 32 + threadIdx.x];
        }
        atomicAdd(&stats[threadIdx.x], ta);
        atomicAdd(&stats[32 + threadIdx.x], tb);
    }
}

extern "C" void kernel_launch(void* const* d_in, const int* in_sizes, int n_in,
                              void* d_out, int out_size, void* d_ws, size_t ws_size,
                              hipStream_t stream) {
    const int N = in_sizes[0] / DIN;
    const int E = in_sizes[2];
    const int N4 = NSPLIT * N;
    const u32 qdiv = (u32)((N + NSPLIT - 1) / NSPLIT);

    const float* x = (const float*)d_in[0];
    const int* ei = (const int*)d_in[1];
    const float* ew = (const float*)d_in[2];
    const int* row = ei;
    const int* col = ei + E;

    const float* Ws[4] = {(const float*)d_in[3], (const float*)d_in[5],
                          (const float*)d_in[7], (const float*)d_in[9]};
    const float* bs[4] = {(const float*)d_in[4], (const float*)d_in[6],
                          (const float*)d_in[8], (const float*)d_in[10]};
    const float* gs[3] = {(const float*)d_in[11], (const float*)d_in[13], (const float*)d_in[15]};
    const float* bes[3] = {(const float*)d_in[12], (const float*)d_in[14], (const float*)d_in[16]};

    // workspace layout (~50 MB)
    char* wsb = (char*)d_ws;
    u64* cnt64 = (u64*)wsb;                          // 4N u64
    float* dinv = (float*)(cnt64 + N4);              // N f32
    int* rowptr = (int*)(dinv + N);                  // 4N+1 int
    int2* esort = (int2*)(rowptr + N4 + 1);          // E int2 (src, norm)
    u16* hbf = (u16*)(esort + E);                    // N*HID bf16 (gemm out)
    float* bufX = (float*)(hbf + (size_t)N * HID);   // N*HID f32 (raw agg accumulator)
    float* stats = bufX + (size_t)N * HID;           // 192 (3 layers x 64)
    int* bsum1 = (int*)(stats + 192);                // 2048
    int* bsum2 = bsum1 + 2048;                       // 512
    int* rank = (int*)bufX;  // E ints aliased: rank dead before bufX first written

    const int B = 256;
    const int ngrid = (N + B - 1) / B;
    const int n4grid = (N4 + B - 1) / B;
    const int egrid = (E + B - 1) / B;
    const int nodeGrid = (N + 7) / 8;
    const int B1 = (N4 + 255) / 256;          // level-1 scan blocks
    const int B2 = (B1 + 255) / 256;          // level-2
    const float invN = 1.0f / (float)N;

    // ---- build split CSR + norm ----
    init_cnt<<<n4grid, B, 0, stream>>>(cnt64, stats, N4);
    hist_rank<<<egrid, B, 0, stream>>>(row, col, ew, cnt64, rank, E, N, qdiv);
    finalize_deg<<<ngrid, B, 0, stream>>>(cnt64, rowptr, dinv, N);
    scan_blocks<<<B1, 256, 0, stream>>>(rowptr, bsum1, N4);
    scan_blocks<<<B2, 256, 0, stream>>>(bsum1, bsum2, B1);
    scan_tops<<<1, 512, 0, stream>>>(bsum2, B2);
    scan_addback<<<B2, 256, 0, stream>>>(bsum1, bsum2, B1, 0);
    scan_addback<<<B1, 256, 0, stream>>>(rowptr, bsum1, N4, E);     // rowptr[4N] = E
    scatter_pos<<<egrid, B, 0, stream>>>(row, col, ew, dinv, rowptr, rank, esort, E, N, qdiv);

    // ---- layers ----
    for (int l = 0; l < 4; ++l) {
        if (l == 0)
            gemm_din<<<nodeGrid, B, 0, stream>>>(x, Ws[0], hbf, N);
        else
            gemm_hid_bn<<<nodeGrid, B, 0, stream>>>(bufX, Ws[l], stats + 64 * (l - 1),
                                                    gs[l - 1], bes[l - 1], hbf, N, invN);

        // 4 sequential quartile passes: pass q's h slice is L2-resident
        for (int q = 0; q < NSPLIT; ++q) {
            int first = (q == 0) ? 1 : 0;
            int last = (q == NSPLIT - 1);
            float* outp = (l == 3 && last) ? (float*)d_out : bufX;
            int flags = first | ((l == 3 && last) ? 2 : 0);
            gather_pass<<<nodeGrid, B, 0, stream>>>((const u32*)hbf, rowptr + (size_t)q * N,
                                                    esort, dinv, bs[l], bufX, outp, N, flags);
        }

        if (l < 3)
            bn_reduce<<<512, B, 0, stream>>>(bufX, stats + 64 * l, N);
    }
}

// Round 10
// 843.196 us; speedup vs baseline: 1.1478x; 1.1478x over previous
//
#include <hip/hip_runtime.h>
#include <hip/hip_bf16.h>

#define DIN 128
#define HID 32
#define EPS 1e-5f
#define FXS 16777216.0f             // 2^24 fixed-point scale for deg accumulation
#define FXI 5.9604644775390625e-8f  // 2^-24

typedef unsigned int u32;
typedef unsigned short u16;
typedef unsigned long long u64;

// extract bf16 half of a packed u32 (hi=0 -> low 16 bits = even channel) as float
__device__ __forceinline__ float bfx(u32 v, int hi) {
    return __uint_as_float(hi ? (v & 0xffff0000u) : (v << 16));
}

__device__ __forceinline__ u16 f2bf(float f) {
    __hip_bfloat16 h = __float2bfloat16(f);
    return *reinterpret_cast<u16*>(&h);
}

// ---------------- init: zero u64 count/deg accumulator + BN stats ----------------
__global__ void init_cnt(u64* __restrict__ cnt64, float* __restrict__ stats, int n) {
    int i = blockIdx.x * blockDim.x + threadIdx.x;
    if (i < n) cnt64[i] = 0ull;
    if (i < 192) stats[i] = 0.f;
}

// one u64 atomic per edge: count(hi32) + fixpoint w(lo32); old hi32 = rank in bin
__global__ void hist_rank(const int* __restrict__ col, const float* __restrict__ w,
                          u64* __restrict__ cnt64, int* __restrict__ rank, int E) {
    int e = blockIdx.x * blockDim.x + threadIdx.x;
    if (e < E) {
        int c = col[e];
        u32 fx = (u32)(w[e] * FXS + 0.5f);
        u64 old = atomicAdd(&cnt64[c], (1ull << 32) | (u64)fx);
        rank[e] = (int)(old >> 32);
    }
}

// counts -> rowptr (pre-scan), deg -> dinv
__global__ void finalize_deg(const u64* __restrict__ cnt64, int* __restrict__ rowptr,
                             float* __restrict__ dinv, int n) {
    int i = blockIdx.x * blockDim.x + threadIdx.x;
    if (i < n) {
        u64 v = cnt64[i];
        rowptr[i] = (int)(v >> 32);
        dinv[i] = rsqrtf(1.0f + (float)(u32)v * FXI);  // +1 self loop
    }
}

// ---------------- exclusive scan over rowptr[0..n) ----------------
__global__ void scan_blocks(int* __restrict__ data, int* __restrict__ bsum, int n) {
    __shared__ int s[256];
    int i = blockIdx.x * 256 + threadIdx.x;
    int v = (i < n) ? data[i] : 0;
    s[threadIdx.x] = v;
    __syncthreads();
    for (int off = 1; off < 256; off <<= 1) {
        int t = (threadIdx.x >= off) ? s[threadIdx.x - off] : 0;
        __syncthreads();
        s[threadIdx.x] += t;
        __syncthreads();
    }
    if (i < n) data[i] = s[threadIdx.x] - v;  // exclusive
    if (threadIdx.x == 255) bsum[blockIdx.x] = s[255];
}

__global__ void scan_tops(int* __restrict__ bsum, int nb) {
    __shared__ int s[512];
    int v = (threadIdx.x < nb) ? bsum[threadIdx.x] : 0;
    s[threadIdx.x] = v;
    __syncthreads();
    for (int off = 1; off < 512; off <<= 1) {
        int t = (threadIdx.x >= off) ? s[threadIdx.x - off] : 0;
        __syncthreads();
        s[threadIdx.x] += t;
        __syncthreads();
    }
    if (threadIdx.x < nb) bsum[threadIdx.x] = s[threadIdx.x] - v;  // exclusive
}

__global__ void scan_addback(int* __restrict__ data, const int* __restrict__ bsum,
                             int n, int E) {
    int i = blockIdx.x * 256 + threadIdx.x;
    if (i < n) data[i] += bsum[blockIdx.x];
    if (i == n) data[n] = E;  // sentinel end
}

// ---------------- atomic-free scatter into CSR, 4-byte packed entries ----------------
// entry = (src << 15) | bf16_bits(norm); norm >= 0 so bf16 sign bit = 0 (15 bits)
__global__ void scatter_pos(const int* __restrict__ row, const int* __restrict__ col,
                            const float* __restrict__ w, const float* __restrict__ dinv,
                            const int* __restrict__ rowptr, const int* __restrict__ rank,
                            u32* __restrict__ esort, int E) {
    int e = blockIdx.x * blockDim.x + threadIdx.x;
    if (e < E) {
        int r = row[e], c = col[e];
        float nv = dinv[r] * w[e] * dinv[c];
        int pos = rowptr[c] + rank[e];
        esort[pos] = ((u32)r << 15) | (u32)f2bf(nv);
    }
}

// ---------------- layer-0 GEMM (x fp32 -> h bf16, split-major halves) ----------------
// hbf layout: half h at hbf[h*n*16 + node*16 + c], c in [0,16)
__global__ void gemm_din(const float* __restrict__ x, const float* __restrict__ W,
                         u16* __restrict__ hbf, int n) {
    __shared__ float Wl[DIN * HID];
    for (int i = threadIdx.x; i < DIN * HID; i += blockDim.x) Wl[i] = W[i];
    __syncthreads();
    int ch = threadIdx.x & 31;
    int node = blockIdx.x * 8 + (threadIdx.x >> 5);
    if (node >= n) return;
    const float* xr = x + (size_t)node * DIN;
    float acc = 0.f;
#pragma unroll 8
    for (int k = 0; k < DIN; ++k) acc += xr[k] * Wl[k * HID + ch];
    hbf[(size_t)(ch >> 4) * n * 16 + node * 16 + (ch & 15)] = f2bf(acc);
}

// ---------------- hidden GEMM, fused BN+ReLU on input (split-major agg in/out) -------
__global__ void gemm_hid_bn(const float* __restrict__ aS, const float* __restrict__ W,
                            const float* __restrict__ stats, const float* __restrict__ g,
                            const float* __restrict__ be, u16* __restrict__ hbf,
                            int n, float invN) {
    __shared__ float Wl[HID * HID];
    __shared__ float sc[HID], sh[HID];
    int t = threadIdx.x;
    for (int i = t; i < HID * HID; i += blockDim.x) Wl[i] = W[i];
    if (t < HID) {
        float mu = stats[t] * invN;
        float var = stats[32 + t] * invN - mu * mu;
        float s = rsqrtf(var + EPS) * g[t];
        sc[t] = s;
        sh[t] = be[t] - mu * s;
    }
    __syncthreads();
    int ch = t & 31;
    int node = blockIdx.x * 8 + (t >> 5);
    if (node >= n) return;
    float acc = 0.f;
#pragma unroll
    for (int k = 0; k < HID; ++k) {
        float av = aS[(size_t)(k >> 4) * n * 16 + node * 16 + (k & 15)];
        float v = fmaxf(av * sc[k] + sh[k], 0.f);
        acc += v * Wl[k * HID + ch];
    }
    hbf[(size_t)(ch >> 4) * n * 16 + node * 16 + (ch & 15)] = f2bf(acc);
}

// ---------------- channel-half CSR gather ----------------
// h2 = this half's packed rows (8 u32/node, 32 B/row, 3.2 MB -> L2-resident).
// out = this half's OWN contiguous region (no cross-kernel line sharing):
// out[node*16 + c]. 16 lanes per node.
__global__ void gather_half(const u32* __restrict__ h2, const int* __restrict__ rowptr,
                            const u32* __restrict__ esort, const float* __restrict__ dinv,
                            const float* __restrict__ b, float* __restrict__ out,
                            int n, int half) {
    int c = threadIdx.x & 15;
    int node = blockIdx.x * 16 + (threadIdx.x >> 4);
    if (node >= n) return;
    int p = c >> 1, hi = c & 1;
    float dv = dinv[node];
    float acc = dv * dv * bfx(h2[node * 8 + p], hi) + b[half * 16 + c];
    int start = rowptr[node], end = rowptr[node + 1];
    int j = start;
    for (; j + 4 <= end; j += 4) {
        u32 e0 = esort[j];
        u32 e1 = esort[j + 1];
        u32 e2 = esort[j + 2];
        u32 e3 = esort[j + 3];
        u32 v0 = h2[(e0 >> 15) * 8 + p];
        u32 v1 = h2[(e1 >> 15) * 8 + p];
        u32 v2 = h2[(e2 >> 15) * 8 + p];
        u32 v3 = h2[(e3 >> 15) * 8 + p];
        acc += __uint_as_float((e0 & 0x7fffu) << 16) * bfx(v0, hi);
        acc += __uint_as_float((e1 & 0x7fffu) << 16) * bfx(v1, hi);
        acc += __uint_as_float((e2 & 0x7fffu) << 16) * bfx(v2, hi);
        acc += __uint_as_float((e3 & 0x7fffu) << 16) * bfx(v3, hi);
    }
    for (; j < end; ++j) {
        u32 ed = esort[j];
        acc += __uint_as_float((ed & 0x7fffu) << 16) * bfx(h2[(ed >> 15) * 8 + p], hi);
    }
    out[node * 16 + c] = acc;
}

// ---------------- BN stats reduce (split-major agg) ----------------
__global__ void bn_reduce(const float* __restrict__ aS, float* __restrict__ stats, int n) {
    __shared__ float s1[256], s2[256];
    int ch = threadIdx.x & 31, rg = threadIdx.x >> 5;
    size_t base = (size_t)(ch >> 4) * n * 16 + (ch & 15);
    float a = 0.f, b = 0.f;
    for (int node = blockIdx.x * 8 + rg; node < n; node += gridDim.x * 8) {
        float v = aS[base + node * 16];
        a += v;
        b += v * v;
    }
    s1[threadIdx.x] = a;
    s2[threadIdx.x] = b;
    __syncthreads();
    if (threadIdx.x < 32) {
        float ta = 0.f, tb = 0.f;
#pragma unroll
        for (int j = 0; j < 8; ++j) {
            ta += s1[j * 32 + threadIdx.x];
            tb += s2[j * 32 + threadIdx.x];
        }
        atomicAdd(&stats[threadIdx.x], ta);
        atomicAdd(&stats[32 + threadIdx.x], tb);
    }
}

// ---------------- final merge: split-major agg -> node-major d_out with ReLU --------
__global__ void merge_relu(const float* __restrict__ aS, float* __restrict__ out, int n) {
    int gid = blockIdx.x * blockDim.x + threadIdx.x;
    if (gid >= n * HID) return;
    int node = gid >> 5, ch = gid & 31;
    float v = aS[(size_t)(ch >> 4) * n * 16 + node * 16 + (ch & 15)];
    out[gid] = fmaxf(v, 0.f);
}

extern "C" void kernel_launch(void* const* d_in, const int* in_sizes, int n_in,
                              void* d_out, int out_size, void* d_ws, size_t ws_size,
                              hipStream_t stream) {
    const int N = in_sizes[0] / DIN;
    const int E = in_sizes[2];

    const float* x = (const float*)d_in[0];
    const int* ei = (const int*)d_in[1];
    const float* ew = (const float*)d_in[2];
    const int* row = ei;
    const int* col = ei + E;

    const float* Ws[4] = {(const float*)d_in[3], (const float*)d_in[5],
                          (const float*)d_in[7], (const float*)d_in[9]};
    const float* bs[4] = {(const float*)d_in[4], (const float*)d_in[6],
                          (const float*)d_in[8], (const float*)d_in[10]};
    const float* gs[3] = {(const float*)d_in[11], (const float*)d_in[13], (const float*)d_in[15]};
    const float* bes[3] = {(const float*)d_in[12], (const float*)d_in[14], (const float*)d_in[16]};

    // workspace layout, every buffer 256B-aligned (~34 MB total)
    char* wsb = (char*)d_ws;
    size_t off = 0;
    auto alloc = [&](size_t bytes) -> void* {
        off = (off + 255) & ~(size_t)255;
        void* p = wsb + off;
        off += bytes;
        return p;
    };
    u64* cnt64 = (u64*)alloc((size_t)N * 8);
    float* dinv = (float*)alloc((size_t)N * 4);
    int* rowptr = (int*)alloc((size_t)(N + 1) * 4);
    u32* esort = (u32*)alloc((size_t)E * 4);
    u16* hbf = (u16*)alloc((size_t)N * HID * 2);    // bf16, split-major halves
    float* aggS = (float*)alloc((size_t)N * HID * 4);  // f32, split-major halves
    float* stats = (float*)alloc(192 * 4);
    int* bsum = (int*)alloc(512 * 4);
    int* rank = (int*)aggS;  // E ints alias aggS: rank dead before aggS first written

    const int B = 256;
    const int ngrid = (N + B - 1) / B;
    const int egrid = (E + B - 1) / B;
    const int nodeGrid8 = (N + 7) / 8;
    const int nodeGrid16 = (N + 15) / 16;
    const int ngrid32 = (N * HID + B - 1) / B;
    const int scanBlocks = (N + 255) / 256;  // 391 <= 512
    const float invN = 1.0f / (float)N;

    // ---- build CSR + norm ----
    init_cnt<<<ngrid, B, 0, stream>>>(cnt64, stats, N);
    hist_rank<<<egrid, B, 0, stream>>>(col, ew, cnt64, rank, E);
    finalize_deg<<<ngrid, B, 0, stream>>>(cnt64, rowptr, dinv, N);
    scan_blocks<<<scanBlocks, 256, 0, stream>>>(rowptr, bsum, N);
    scan_tops<<<1, 512, 0, stream>>>(bsum, scanBlocks);
    scan_addback<<<scanBlocks + 1, 256, 0, stream>>>(rowptr, bsum, N, E);
    scatter_pos<<<egrid, B, 0, stream>>>(row, col, ew, dinv, rowptr, rank, esort, E);

    // ---- layers ----
    for (int l = 0; l < 4; ++l) {
        if (l == 0)
            gemm_din<<<nodeGrid8, B, 0, stream>>>(x, Ws[0], hbf, N);
        else
            gemm_hid_bn<<<nodeGrid8, B, 0, stream>>>(aggS, Ws[l], stats + 64 * (l - 1),
                                                     gs[l - 1], bes[l - 1], hbf, N, invN);

        // two channel-half passes; each touches only its 3.2 MB h-half and writes
        // its own contiguous 6.4 MB agg region (no cross-kernel line sharing)
        gather_half<<<nodeGrid16, B, 0, stream>>>((const u32*)hbf, rowptr, esort, dinv,
                                                  bs[l], aggS, N, 0);
        gather_half<<<nodeGrid16, B, 0, stream>>>((const u32*)(hbf + (size_t)N * 16),
                                                  rowptr, esort, dinv, bs[l],
                                                  aggS + (size_t)N * 16, N, 1);

        if (l < 3)
            bn_reduce<<<512, B, 0, stream>>>(aggS, stats + 64 * l, N);
        else
            merge_relu<<<ngrid32, B, 0, stream>>>(aggS, (float*)d_out, N);
    }
}